// Round 10
// baseline (295.835 us; speedup 1.0000x reference)
//
#include <hip/hip_runtime.h>
#include <hip/hip_bf16.h>
#include <math.h>

typedef short bf16x8 __attribute__((ext_vector_type(8)));
typedef float f32x4 __attribute__((ext_vector_type(4)));
typedef float f32x16 __attribute__((ext_vector_type(16)));

#if __has_builtin(__builtin_amdgcn_exp2f)
#define EXP2F(x) __builtin_amdgcn_exp2f(x)
#else
#define EXP2F(x) __expf(0.69314718056f * (x))
#endif

__device__ __forceinline__ unsigned short f2bf(float f) {
    union { float f; unsigned u; } v; v.f = f;
    unsigned r = v.u + 0x7fffu + ((v.u >> 16) & 1u);   // RNE
    return (unsigned short)(r >> 16);
}

__device__ __forceinline__ unsigned pack_bf2(float a, float b) {
    __hip_bfloat162 h = __float22bfloat162_rn(float2{a, b});
    union { __hip_bfloat162 h; unsigned u; } c; c.h = h;
    return c.u;
}

__device__ __forceinline__ void gld_lds16(const unsigned short* g, const unsigned short* l) {
    __builtin_amdgcn_global_load_lds(
        (const __attribute__((address_space(1))) void*)g,
        (__attribute__((address_space(3))) void*)l, 16, 0, 0);
}

// ---------- fp32 -> bf16 converts ----------
__global__ void cvt_f32_bf16(const float* __restrict__ src, unsigned short* __restrict__ dst, int n) {
    int i = (blockIdx.x * blockDim.x + threadIdx.x) * 4;
    if (i < n) {
        float4 f = *(const float4*)(src + i);
        ushort4 o;
        o.x = f2bf(f.x); o.y = f2bf(f.y); o.z = f2bf(f.z); o.w = f2bf(f.w);
        *(ushort4*)(dst + i) = o;
    }
}

__global__ void cvt4_f32_bf16(const float* s0, const float* s1, const float* s2, const float* s3,
                              unsigned short* d0, unsigned short* d1, unsigned short* d2,
                              unsigned short* d3, int n) {
    const float* s; unsigned short* d;
    switch (blockIdx.y) {
        case 0: s = s0; d = d0; break;
        case 1: s = s1; d = d1; break;
        case 2: s = s2; d = d2; break;
        default: s = s3; d = d3; break;
    }
    int i = (blockIdx.x * blockDim.x + threadIdx.x) * 4;
    if (i < n) {
        float4 f = *(const float4*)(s + i);
        ushort4 o;
        o.x = f2bf(f.x); o.y = f2bf(f.y); o.z = f2bf(f.z); o.w = f2bf(f.w);
        *(ushort4*)(d + i) = o;
    }
}

// token mask -> additive float (0 / -inf)
__global__ void mask_to_f(const int* __restrict__ tm, float* __restrict__ ma, int n) {
    int i = blockIdx.x * blockDim.x + threadIdx.x;
    if (i < n) ma[i] = tm[i] ? 0.0f : -__builtin_inff();
}

// ---------- GEMM: C[M,Nlog] = A[M,K] @ W[Nlog,K]^T + bias ----------
// Double-buffered LDS + single barrier per K-iter: sync (cur landed) ->
// issue DMA for next into alt -> compute cur. Loads overlap full compute.
// Fused QKV (Nlog=3072): buf = n0>>10 selects Q/K/V; V (buf 2) stored
// TRANSPOSED to vt as [b*16+h][d][t] (packed ushort4 along t) for attn DMA.
__global__ __launch_bounds__(256, 4) void gemm_bt(
        const unsigned short* __restrict__ A, const unsigned short* __restrict__ W,
        const float* __restrict__ b0p, const float* __restrict__ b1p,
        const float* __restrict__ b2p, float* __restrict__ outF,
        unsigned short* __restrict__ outB, unsigned short* __restrict__ vt,
        int M, int Nlog, int K) {
    __shared__ __align__(16) unsigned short As[2][128][32];   // 8 KB x2
    __shared__ __align__(16) unsigned short Ws[2][128][32];   // 8 KB x2
    const size_t BUFS = (size_t)8192 * 1024;
    const int m0 = blockIdx.y * 128, n0 = blockIdx.x * 128;
    const int tid = threadIdx.x, lane = tid & 63, w = tid >> 6;
    const int quad = lane >> 4, lc = lane & 15;
    const int wr = (w >> 1) * 64, wc = (w & 1) * 64;
    const int sr = lane >> 2, sc = (lane & 3) * 8;

    const int buf = n0 >> 10;
    const float* bias = buf == 0 ? b0p : (buf == 1 ? b1p : b2p);

    auto stage = [&](int s, int k0) {
        gld_lds16(A + (size_t)(m0 + w * 32 +      sr) * K + k0 + sc, &As[s][w * 32     ][0]);
        gld_lds16(A + (size_t)(m0 + w * 32 + 16 + sr) * K + k0 + sc, &As[s][w * 32 + 16][0]);
        gld_lds16(W + (size_t)(n0 + w * 32 +      sr) * K + k0 + sc, &Ws[s][w * 32     ][0]);
        gld_lds16(W + (size_t)(n0 + w * 32 + 16 + sr) * K + k0 + sc, &Ws[s][w * 32 + 16][0]);
    };

    f32x4 acc[4][4] = {};
    stage(0, 0);

    for (int k0 = 0; k0 < K; k0 += 32) {
        const int cur = (k0 >> 5) & 1;
        __syncthreads();                       // As/Ws[cur] landed (vmcnt drain)
        if (k0 + 32 < K) stage(cur ^ 1, k0 + 32);   // lands by next sync
        bf16x8 af[4], bw[4];
        #pragma unroll
        for (int i = 0; i < 4; ++i) af[i] = *(const bf16x8*)&As[cur][wr + i * 16 + lc][quad * 8];
        #pragma unroll
        for (int j = 0; j < 4; ++j) bw[j] = *(const bf16x8*)&Ws[cur][wc + j * 16 + lc][quad * 8];
        #pragma unroll
        for (int i = 0; i < 4; ++i)
            #pragma unroll
            for (int j = 0; j < 4; ++j)
                acc[i][j] = __builtin_amdgcn_mfma_f32_16x16x32_bf16(af[i], bw[j], acc[i][j], 0, 0, 0);
    }

    #pragma unroll
    for (int j = 0; j < 4; ++j) {
        int col = n0 + wc + j * 16 + lc;
        int coll = col & 1023;
        float bj = bias[coll];
        #pragma unroll
        for (int i = 0; i < 4; ++i) {
            int rowb = m0 + wr + i * 16 + quad * 4;
            if (buf == 2) {
                // V^T store: [b*16+h][d][t], t = rowb..rowb+3 contiguous (8B)
                int bb = rowb >> 11, t = rowb & 2047;
                int hh = coll >> 6, dd = coll & 63;
                ushort4 o4;
                o4.x = f2bf(acc[i][j][0] + bj);
                o4.y = f2bf(acc[i][j][1] + bj);
                o4.z = f2bf(acc[i][j][2] + bj);
                o4.w = f2bf(acc[i][j][3] + bj);
                *(ushort4*)(vt + ((size_t)(bb * 16 + hh) * 64 + dd) * 2048 + t) = o4;
            } else {
                #pragma unroll
                for (int r = 0; r < 4; ++r) {
                    float v = acc[i][j][r] + bj;
                    size_t idx = (size_t)buf * BUFS + (size_t)(rowb + r) * 1024 + coll;
                    if (outB) outB[idx] = f2bf(v);
                    else      outF[idx] = v;
                }
            }
        }
    }
}

// ---------- flash attention, 32x32-MFMA swapped-operand structure ----------
// R8 base (KVBLK=128: two 64-row K/V sub-tiles per barrier, paired
// q-blocks, XCD-pinned bh, float maskadd, __shfl_xor cross-half combine --
// all R8-passing). R10 change: TREE REDUCTIONS ONLY -- depth-5 pairwise
// trees replace the serial 32-op fmax/add chains (pure reassociation).
// The double-permlane cross-half combine is BANNED: R4 and R9 both failed
// with identical absmax 1.496 and it was their only shared element; the
// duplicated-SSA tied-operand asm pattern miscompiles. Only proven-safe
// permlane use is the pb-packing (4 distinct live operands).
__global__ __launch_bounds__(256, 2) void attn_kernel(
        const unsigned short* __restrict__ Q, const unsigned short* __restrict__ K,
        const unsigned short* __restrict__ Vt, const float* __restrict__ maskadd,
        unsigned short* __restrict__ O) {
    const int T = 2048, C = 1024;
    __shared__ __align__(16) unsigned short Kl[2][2][64][64];   // 32 KB: dbuf x subtile
    __shared__ __align__(16) unsigned short Vl[2][2][64][64];   // 32 KB

    // XCD swizzle: all 8 pair-blocks of a bh on one XCD (R1-identical)
    const int lid = blockIdx.y * 8 + blockIdx.x;         // 0..511, XCD = lid & 7
    const int sw = (lid & 7) * 64 + (lid >> 3);
    const int pair = sw & 7;                             // 0..7
    const int bn = sw >> 3;                              // 0..63
    const int b = bn >> 4, h = bn & 15;

    const int tid = threadIdx.x, w = tid >> 6, lane = tid & 63;
    const int lq = lane & 31, hi = lane >> 5;
    const float NEG_INF = -__builtin_inff();
    const float CSC = 0.18033688011112042f;   // 0.125 * log2(e)

    const unsigned short* Kbh = K + (size_t)b * T * C + h * 64;            // [t][1024]
    const unsigned short* Vbh = Vt + (size_t)(b * 16 + h) * 64 * 2048;     // [d][2048]

    const int lrow = lane >> 3;
    const int swz8 = ((lane & 7) ^ (lrow & 7)) * 8;    // staging source swizzle
    const int rdsw = lq & 7;                           // reader row-xor

    // stage double-tile s2 (k rows s2*128 .. +127) into slot s
    auto stageK2 = [&](int s2, int s) {
        #pragma unroll
        for (int cc = 0; cc < 2; ++cc)
            #pragma unroll
            for (int ch = 0; ch < 2; ++ch)
                gld_lds16(Kbh + (size_t)(s2 * 128 + cc * 64 + w * 16 + ch * 8 + lrow) * C + swz8,
                          &Kl[s][cc][w * 16 + ch * 8][0]);
    };
    auto stageV2 = [&](int s2, int s) {
        #pragma unroll
        for (int cc = 0; cc < 2; ++cc)
            #pragma unroll
            for (int ch = 0; ch < 2; ++ch)
                gld_lds16(Vbh + (size_t)(w * 16 + ch * 8 + lrow) * 2048 + s2 * 128 + cc * 64 + swz8,
                          &Vl[s][cc][w * 16 + ch * 8][0]);
    };

    #pragma unroll 1
    for (int half = 0; half < 2; ++half) {
        const int qb = half ? (15 - pair) : pair;      // paired: 17 double-steps total
        const int S2 = qb + 1;                         // double-steps (KT=2qb+2 is even)
        const int Q0 = qb * 128 + w * 32;              // wave's q-base
        const int ktd = Q0 >> 6;                       // wave's diagonal 64-tile
        const int qg = Q0 + lq;                        // lane's global q row

        if (half) __syncthreads();     // protect buffers from late readers of half 0
        stageK2(0, 0);
        stageV2(0, 0);

        // Q B-fragments hoisted: lane holds Q[q=Q0+lq][d = i*16 + hi*8 .. +7]
        const unsigned short* Qp = Q + (size_t)(b * T + Q0 + lq) * C + h * 64 + hi * 8;
        bf16x8 qf[4];
        #pragma unroll
        for (int i = 0; i < 4; ++i) qf[i] = *(const bf16x8*)(Qp + i * 16);

        f32x16 oacc[2] = {};           // O^T [dh*32 + creg(r,hi)][q=lq]
        float m = NEG_INF, l = 0.f;

        #pragma unroll 1
        for (int s2 = 0; s2 < S2; ++s2) {
            const int slot = s2 & 1;
            __syncthreads();                               // K/V[slot] landed (vmcnt drain)
            if (s2 + 1 < S2) {                             // prefetch next double-tile
                stageK2(s2 + 1, slot ^ 1);
                stageV2(s2 + 1, slot ^ 1);
            }

            #pragma unroll
            for (int cc = 0; cc < 2; ++cc) {
                const int kt = 2 * s2 + cc;
                if (kt > ktd) continue;    // fully-masked sub-tile for this wave

                // token-mask values for this lane's 32 k-slots
                f32x4 mkv[8];
                const float* mb = maskadd + b * T + kt * 64 + hi * 4;
                #pragma unroll
                for (int g = 0; g < 8; ++g)
                    mkv[g] = *(const f32x4*)(mb + (g >> 2) * 32 + (g & 3) * 8);

                // S^T = K . Q^T : two 32-row k-halves, contraction d=64 (4 x K=16)
                f32x16 sacc[2] = {};
                __builtin_amdgcn_s_setprio(1);
                #pragma unroll
                for (int kh = 0; kh < 2; ++kh)
                    #pragma unroll
                    for (int i = 0; i < 4; ++i) {
                        bf16x8 kf = *(const bf16x8*)&Kl[slot][cc][kh * 32 + lq][(((i << 1) | hi) ^ rdsw) * 8];
                        sacc[kh] = __builtin_amdgcn_mfma_f32_32x32x16_bf16(kf, qf[i], sacc[kh], 0, 0, 0);
                    }
                __builtin_amdgcn_s_setprio(0);

                // scale + token mask (+ causal only on the wave's diagonal tile)
                const bool diag = (kt == ktd);
                #pragma unroll
                for (int kh = 0; kh < 2; ++kh) {
                    #pragma unroll
                    for (int r = 0; r < 16; ++r) {
                        float x = fmaf(sacc[kh][r], CSC, mkv[kh * 4 + (r >> 2)][r & 3]);
                        if (diag) {
                            int kg = kt * 64 + kh * 32 + (r >> 2) * 8 + hi * 4 + (r & 3);
                            if (kg > qg) x = NEG_INF;
                        }
                        sacc[kh][r] = x;
                    }
                }

                // row max: depth-5 pairwise tree (reassociation only), then
                // the R8-proven shfl_xor cross-half combine
                float mx[16];
                #pragma unroll
                for (int r = 0; r < 16; ++r) mx[r] = fmaxf(sacc[0][r], sacc[1][r]);
                #pragma unroll
                for (int s3 = 8; s3 > 0; s3 >>= 1)
                    #pragma unroll
                    for (int r = 0; r < s3; ++r) mx[r] = fmaxf(mx[r], mx[r + s3]);
                float tmax = fmaxf(mx[0], __shfl_xor(mx[0], 32, 64));

                // defer-max: rescale only when the running max grows past THR
                if (__any(tmax > m + 8.0f)) {
                    float mnew = fmaxf(m, tmax);
                    float al = EXP2F(m - mnew);
                    m = mnew; l *= al;
                    #pragma unroll
                    for (int dh = 0; dh < 2; ++dh)
                        #pragma unroll
                        for (int r = 0; r < 16; ++r) oacc[dh][r] *= al;
                }

                // exp + row-sum tree (same shfl_xor combine)
                float sm[16];
                #pragma unroll
                for (int r = 0; r < 16; ++r) {
                    float p0 = EXP2F(sacc[0][r] - m);
                    float p1 = EXP2F(sacc[1][r] - m);
                    sacc[0][r] = p0; sacc[1][r] = p1;
                    sm[r] = p0 + p1;
                }
                #pragma unroll
                for (int s3 = 8; s3 > 0; s3 >>= 1)
                    #pragma unroll
                    for (int r = 0; r < s3; ++r) sm[r] += sm[r + s3];
                float ps = sm[0];
                ps += __shfl_xor(ps, 32, 64);
                l += ps;

                // P^T B-fragments in-register: cvt_pk pairs + permlane32_swap
                // (proven-safe pattern: all four asm operands distinct live values)
                bf16x8 pb[4];
                #pragma unroll
                for (int i = 0; i < 4; ++i) {
                    const int kh = i >> 1, ro = (i & 1) * 8;
                    unsigned pa = pack_bf2(sacc[kh][ro + 0], sacc[kh][ro + 1]);
                    unsigned pe = pack_bf2(sacc[kh][ro + 4], sacc[kh][ro + 5]);
                    unsigned pc = pack_bf2(sacc[kh][ro + 2], sacc[kh][ro + 3]);
                    unsigned pd = pack_bf2(sacc[kh][ro + 6], sacc[kh][ro + 7]);
                    asm("v_permlane32_swap_b32 %0, %1" : "+v"(pa), "+v"(pe));  // pa=w0, pe=w2
                    asm("v_permlane32_swap_b32 %0, %1" : "+v"(pc), "+v"(pd));  // pc=w1, pd=w3
                    union { unsigned u[4]; bf16x8 v; } uu;
                    uu.u[0] = pa; uu.u[1] = pc; uu.u[2] = pe; uu.u[3] = pd;
                    pb[i] = uu.v;
                }

                // O^T += V^T . P^T : two 32-row d-halves, contraction k=64 (4 x K=16)
                __builtin_amdgcn_s_setprio(1);
                #pragma unroll
                for (int dh = 0; dh < 2; ++dh)
                    #pragma unroll
                    for (int i = 0; i < 4; ++i) {
                        bf16x8 vf = *(const bf16x8*)&Vl[slot][cc][dh * 32 + lq][(((i << 1) | hi) ^ rdsw) * 8];
                        oacc[dh] = __builtin_amdgcn_mfma_f32_32x32x16_bf16(vf, pb[i], oacc[dh], 0, 0, 0);
                    }
                __builtin_amdgcn_s_setprio(0);
            }
        }

        // epilogue: lane owns q = Q0+lq; d = dh*32 + g*8 + hi*4 + 0..3 (8B stores)
        float inv = 1.0f / l;
        size_t orow = (size_t)(b * T + Q0 + lq) * C + h * 64;
        #pragma unroll
        for (int dh = 0; dh < 2; ++dh)
            #pragma unroll
            for (int g = 0; g < 4; ++g) {
                ushort4 o4;
                o4.x = f2bf(oacc[dh][g * 4 + 0] * inv);
                o4.y = f2bf(oacc[dh][g * 4 + 1] * inv);
                o4.z = f2bf(oacc[dh][g * 4 + 2] * inv);
                o4.w = f2bf(oacc[dh][g * 4 + 3] * inv);
                *(ushort4*)(O + orow + dh * 32 + g * 8 + hi * 4) = o4;
            }
    }
}

extern "C" void kernel_launch(void* const* d_in, const int* in_sizes, int n_in,
                              void* d_out, int out_size, void* d_ws, size_t ws_size,
                              hipStream_t stream) {
    const float* x  = (const float*)d_in[0];
    const int* tm   = (const int*)d_in[1];
    const float* wq = (const float*)d_in[2]; const float* bq = (const float*)d_in[3];
    const float* wk = (const float*)d_in[4]; const float* bk = (const float*)d_in[5];
    const float* wv = (const float*)d_in[6]; const float* bv = (const float*)d_in[7];
    const float* wp = (const float*)d_in[8]; const float* bp = (const float*)d_in[9];
    float* out = (float*)d_out;

    const int Bv = 4, Tv = 2048, Cv = 1024;
    const size_t MT = (size_t)Bv * Tv;           // 8192 rows
    const size_t XN = MT * Cv;
    const size_t WN = (size_t)Cv * Cv;

    // layout (bf16): xb | wq wk wv (fused 3072x1024) | wp | Q | K | Vt
    unsigned short* xb  = (unsigned short*)d_ws;
    unsigned short* wqb = xb  + XN;
    unsigned short* wkb = wqb + WN;
    unsigned short* wvb = wkb + WN;
    unsigned short* wpb = wvb + WN;
    unsigned short* Qb  = wpb + WN;
    unsigned short* Kb  = Qb + XN;
    unsigned short* Vtb = Kb + XN;               // transposed V [bh][d][t]
    unsigned short* Ab  = xb;                    // attn output reuses xb
    // maskadd scratch lives at the start of d_out (overwritten by the final
    // projection only after attn completes; stream-ordered => safe)
    float* maskadd = (float*)d_out;

    cvt_f32_bf16<<<XN / 1024, 256, 0, stream>>>(x, xb, (int)XN);
    cvt4_f32_bf16<<<dim3(WN / 1024, 4), 256, 0, stream>>>(wq, wk, wv, wp, wqb, wkb, wvb, wpb, (int)WN);
    mask_to_f<<<(int)(MT / 256), 256, 0, stream>>>(tm, maskadd, (int)MT);

    // fused QKV: logical N = 3072; V portion stored transposed into Vtb
    gemm_bt<<<dim3(24, 64), 256, 0, stream>>>(xb, wqb, bq, bk, bv, nullptr, Qb, Vtb, (int)MT, 3072, Cv);

    attn_kernel<<<dim3(8, Bv * 16), 256, 0, stream>>>(Qb, Kb, Vtb, maskadd, Ab);

    gemm_bt<<<dim3(8, 64), 256, 0, stream>>>(Ab, wpb, bp, bp, bp, out, nullptr, nullptr, (int)MT, 1024, Cv);
}

// Round 11
// 291.166 us; speedup vs baseline: 1.0160x; 1.0160x over previous
//
#include <hip/hip_runtime.h>
#include <hip/hip_bf16.h>
#include <math.h>

typedef short bf16x8 __attribute__((ext_vector_type(8)));
typedef float f32x4 __attribute__((ext_vector_type(4)));
typedef float f32x16 __attribute__((ext_vector_type(16)));

#if __has_builtin(__builtin_amdgcn_exp2f)
#define EXP2F(x) __builtin_amdgcn_exp2f(x)
#else
#define EXP2F(x) __expf(0.69314718056f * (x))
#endif

__device__ __forceinline__ unsigned short f2bf(float f) {
    union { float f; unsigned u; } v; v.f = f;
    unsigned r = v.u + 0x7fffu + ((v.u >> 16) & 1u);   // RNE
    return (unsigned short)(r >> 16);
}

__device__ __forceinline__ unsigned pack_bf2(float a, float b) {
    __hip_bfloat162 h = __float22bfloat162_rn(float2{a, b});
    union { __hip_bfloat162 h; unsigned u; } c; c.h = h;
    return c.u;
}

__device__ __forceinline__ void gld_lds16(const unsigned short* g, const unsigned short* l) {
    __builtin_amdgcn_global_load_lds(
        (const __attribute__((address_space(1))) void*)g,
        (__attribute__((address_space(3))) void*)l, 16, 0, 0);
}

// ---------- fused prep: x->bf16 | 4 weights->bf16 | token mask->additive ----------
// One launch replaces three (launch-gap reduction; the three jobs are
// data-independent). Grid: 8192 x-blocks | 4096 weight-blocks | 32 mask-blocks.
__global__ void prep_all(const float* __restrict__ x,
                         const float* __restrict__ wq, const float* __restrict__ wk,
                         const float* __restrict__ wv, const float* __restrict__ wp,
                         const int* __restrict__ tm,
                         unsigned short* __restrict__ xb,
                         unsigned short* __restrict__ wqb, unsigned short* __restrict__ wkb,
                         unsigned short* __restrict__ wvb, unsigned short* __restrict__ wpb,
                         float* __restrict__ maskadd) {
    const int bid = blockIdx.x;
    if (bid < 8192) {                       // x: 8192 blocks x 256 thr x 4 elems
        int i = (bid * 256 + threadIdx.x) * 4;
        float4 f = *(const float4*)(x + i);
        ushort4 o;
        o.x = f2bf(f.x); o.y = f2bf(f.y); o.z = f2bf(f.z); o.w = f2bf(f.w);
        *(ushort4*)(xb + i) = o;
    } else if (bid < 12288) {               // weights: 1024 blocks each
        int wbid = bid - 8192;
        int which = wbid >> 10;
        const float* s = which == 0 ? wq : (which == 1 ? wk : (which == 2 ? wv : wp));
        unsigned short* d = which == 0 ? wqb : (which == 1 ? wkb : (which == 2 ? wvb : wpb));
        int i = ((wbid & 1023) * 256 + threadIdx.x) * 4;
        float4 f = *(const float4*)(s + i);
        ushort4 o;
        o.x = f2bf(f.x); o.y = f2bf(f.y); o.z = f2bf(f.z); o.w = f2bf(f.w);
        *(ushort4*)(d + i) = o;
    } else {                                // mask: 32 blocks x 256 = 8192 tokens
        int i = (bid - 12288) * 256 + threadIdx.x;
        maskadd[i] = tm[i] ? 0.0f : -__builtin_inff();
    }
}

// ---------- GEMM: C[M,Nlog] = A[M,K] @ W[Nlog,K]^T + bias ----------
// Double-buffered LDS + single barrier per K-iter: sync (cur landed) ->
// issue DMA for next into alt -> compute cur. Loads overlap full compute.
// Fused QKV (Nlog=3072): buf = n0>>10 selects Q/K/V; V (buf 2) stored
// TRANSPOSED to vt as [b*16+h][d][t] (packed ushort4 along t) for attn DMA.
__global__ __launch_bounds__(256, 4) void gemm_bt(
        const unsigned short* __restrict__ A, const unsigned short* __restrict__ W,
        const float* __restrict__ b0p, const float* __restrict__ b1p,
        const float* __restrict__ b2p, float* __restrict__ outF,
        unsigned short* __restrict__ outB, unsigned short* __restrict__ vt,
        int M, int Nlog, int K) {
    __shared__ __align__(16) unsigned short As[2][128][32];   // 8 KB x2
    __shared__ __align__(16) unsigned short Ws[2][128][32];   // 8 KB x2
    const size_t BUFS = (size_t)8192 * 1024;
    const int m0 = blockIdx.y * 128, n0 = blockIdx.x * 128;
    const int tid = threadIdx.x, lane = tid & 63, w = tid >> 6;
    const int quad = lane >> 4, lc = lane & 15;
    const int wr = (w >> 1) * 64, wc = (w & 1) * 64;
    const int sr = lane >> 2, sc = (lane & 3) * 8;

    const int buf = n0 >> 10;
    const float* bias = buf == 0 ? b0p : (buf == 1 ? b1p : b2p);

    auto stage = [&](int s, int k0) {
        gld_lds16(A + (size_t)(m0 + w * 32 +      sr) * K + k0 + sc, &As[s][w * 32     ][0]);
        gld_lds16(A + (size_t)(m0 + w * 32 + 16 + sr) * K + k0 + sc, &As[s][w * 32 + 16][0]);
        gld_lds16(W + (size_t)(n0 + w * 32 +      sr) * K + k0 + sc, &Ws[s][w * 32     ][0]);
        gld_lds16(W + (size_t)(n0 + w * 32 + 16 + sr) * K + k0 + sc, &Ws[s][w * 32 + 16][0]);
    };

    f32x4 acc[4][4] = {};
    stage(0, 0);

    for (int k0 = 0; k0 < K; k0 += 32) {
        const int cur = (k0 >> 5) & 1;
        __syncthreads();                       // As/Ws[cur] landed (vmcnt drain)
        if (k0 + 32 < K) stage(cur ^ 1, k0 + 32);   // lands by next sync
        bf16x8 af[4], bw[4];
        #pragma unroll
        for (int i = 0; i < 4; ++i) af[i] = *(const bf16x8*)&As[cur][wr + i * 16 + lc][quad * 8];
        #pragma unroll
        for (int j = 0; j < 4; ++j) bw[j] = *(const bf16x8*)&Ws[cur][wc + j * 16 + lc][quad * 8];
        #pragma unroll
        for (int i = 0; i < 4; ++i)
            #pragma unroll
            for (int j = 0; j < 4; ++j)
                acc[i][j] = __builtin_amdgcn_mfma_f32_16x16x32_bf16(af[i], bw[j], acc[i][j], 0, 0, 0);
    }

    #pragma unroll
    for (int j = 0; j < 4; ++j) {
        int col = n0 + wc + j * 16 + lc;
        int coll = col & 1023;
        float bj = bias[coll];
        #pragma unroll
        for (int i = 0; i < 4; ++i) {
            int rowb = m0 + wr + i * 16 + quad * 4;
            if (buf == 2) {
                // V^T store: [b*16+h][d][t], t = rowb..rowb+3 contiguous (8B)
                int bb = rowb >> 11, t = rowb & 2047;
                int hh = coll >> 6, dd = coll & 63;
                ushort4 o4;
                o4.x = f2bf(acc[i][j][0] + bj);
                o4.y = f2bf(acc[i][j][1] + bj);
                o4.z = f2bf(acc[i][j][2] + bj);
                o4.w = f2bf(acc[i][j][3] + bj);
                *(ushort4*)(vt + ((size_t)(bb * 16 + hh) * 64 + dd) * 2048 + t) = o4;
            } else {
                #pragma unroll
                for (int r = 0; r < 4; ++r) {
                    float v = acc[i][j][r] + bj;
                    size_t idx = (size_t)buf * BUFS + (size_t)(rowb + r) * 1024 + coll;
                    if (outB) outB[idx] = f2bf(v);
                    else      outF[idx] = v;
                }
            }
        }
    }
}

// ---------- flash attention, 32x32-MFMA swapped-operand structure ----------
// R8-EXACT revert (best passing: 90.8 us). KVBLK=128: two 64-row K/V
// sub-tiles per barrier; paired q-blocks (qb, 15-qb); XCD-pinned bh;
// float maskadd; serial max/sum chains + __shfl_xor(32) combine (R10's
// tree rework measured -2.3us => reverted); proven permlane pb-packing.
__global__ __launch_bounds__(256, 2) void attn_kernel(
        const unsigned short* __restrict__ Q, const unsigned short* __restrict__ K,
        const unsigned short* __restrict__ Vt, const float* __restrict__ maskadd,
        unsigned short* __restrict__ O) {
    const int T = 2048, C = 1024;
    __shared__ __align__(16) unsigned short Kl[2][2][64][64];   // 32 KB: dbuf x subtile
    __shared__ __align__(16) unsigned short Vl[2][2][64][64];   // 32 KB

    // XCD swizzle: all 8 pair-blocks of a bh on one XCD (R1-identical)
    const int lid = blockIdx.y * 8 + blockIdx.x;         // 0..511, XCD = lid & 7
    const int sw = (lid & 7) * 64 + (lid >> 3);
    const int pair = sw & 7;                             // 0..7
    const int bn = sw >> 3;                              // 0..63
    const int b = bn >> 4, h = bn & 15;

    const int tid = threadIdx.x, w = tid >> 6, lane = tid & 63;
    const int lq = lane & 31, hi = lane >> 5;
    const float NEG_INF = -__builtin_inff();
    const float CSC = 0.18033688011112042f;   // 0.125 * log2(e)

    const unsigned short* Kbh = K + (size_t)b * T * C + h * 64;            // [t][1024]
    const unsigned short* Vbh = Vt + (size_t)(b * 16 + h) * 64 * 2048;     // [d][2048]

    const int lrow = lane >> 3;
    const int swz8 = ((lane & 7) ^ (lrow & 7)) * 8;    // staging source swizzle
    const int rdsw = lq & 7;                           // reader row-xor

    // stage double-tile s2 (k rows s2*128 .. +127) into slot s
    auto stageK2 = [&](int s2, int s) {
        #pragma unroll
        for (int cc = 0; cc < 2; ++cc)
            #pragma unroll
            for (int ch = 0; ch < 2; ++ch)
                gld_lds16(Kbh + (size_t)(s2 * 128 + cc * 64 + w * 16 + ch * 8 + lrow) * C + swz8,
                          &Kl[s][cc][w * 16 + ch * 8][0]);
    };
    auto stageV2 = [&](int s2, int s) {
        #pragma unroll
        for (int cc = 0; cc < 2; ++cc)
            #pragma unroll
            for (int ch = 0; ch < 2; ++ch)
                gld_lds16(Vbh + (size_t)(w * 16 + ch * 8 + lrow) * 2048 + s2 * 128 + cc * 64 + swz8,
                          &Vl[s][cc][w * 16 + ch * 8][0]);
    };

    #pragma unroll 1
    for (int half = 0; half < 2; ++half) {
        const int qb = half ? (15 - pair) : pair;      // paired: 17 double-steps total
        const int S2 = qb + 1;                         // double-steps (KT=2qb+2 is even)
        const int Q0 = qb * 128 + w * 32;              // wave's q-base
        const int ktd = Q0 >> 6;                       // wave's diagonal 64-tile
        const int qg = Q0 + lq;                        // lane's global q row

        if (half) __syncthreads();     // protect buffers from late readers of half 0
        stageK2(0, 0);
        stageV2(0, 0);

        // Q B-fragments hoisted: lane holds Q[q=Q0+lq][d = i*16 + hi*8 .. +7]
        const unsigned short* Qp = Q + (size_t)(b * T + Q0 + lq) * C + h * 64 + hi * 8;
        bf16x8 qf[4];
        #pragma unroll
        for (int i = 0; i < 4; ++i) qf[i] = *(const bf16x8*)(Qp + i * 16);

        f32x16 oacc[2] = {};           // O^T [dh*32 + creg(r,hi)][q=lq]
        float m = NEG_INF, l = 0.f;

        #pragma unroll 1
        for (int s2 = 0; s2 < S2; ++s2) {
            const int slot = s2 & 1;
            __syncthreads();                               // K/V[slot] landed (vmcnt drain)
            if (s2 + 1 < S2) {                             // prefetch next double-tile
                stageK2(s2 + 1, slot ^ 1);
                stageV2(s2 + 1, slot ^ 1);
            }

            #pragma unroll
            for (int cc = 0; cc < 2; ++cc) {
                const int kt = 2 * s2 + cc;
                if (kt > ktd) continue;    // fully-masked sub-tile for this wave

                // token-mask values for this lane's 32 k-slots
                f32x4 mkv[8];
                const float* mb = maskadd + b * T + kt * 64 + hi * 4;
                #pragma unroll
                for (int g = 0; g < 8; ++g)
                    mkv[g] = *(const f32x4*)(mb + (g >> 2) * 32 + (g & 3) * 8);

                // S^T = K . Q^T : two 32-row k-halves, contraction d=64 (4 x K=16)
                f32x16 sacc[2] = {};
                __builtin_amdgcn_s_setprio(1);
                #pragma unroll
                for (int kh = 0; kh < 2; ++kh)
                    #pragma unroll
                    for (int i = 0; i < 4; ++i) {
                        bf16x8 kf = *(const bf16x8*)&Kl[slot][cc][kh * 32 + lq][(((i << 1) | hi) ^ rdsw) * 8];
                        sacc[kh] = __builtin_amdgcn_mfma_f32_32x32x16_bf16(kf, qf[i], sacc[kh], 0, 0, 0);
                    }
                __builtin_amdgcn_s_setprio(0);

                // scale + token mask (+ causal only on the wave's diagonal tile)
                float tmax = NEG_INF;
                const bool diag = (kt == ktd);
                #pragma unroll
                for (int kh = 0; kh < 2; ++kh) {
                    #pragma unroll
                    for (int r = 0; r < 16; ++r) {
                        float x = fmaf(sacc[kh][r], CSC, mkv[kh * 4 + (r >> 2)][r & 3]);
                        if (diag) {
                            int kg = kt * 64 + kh * 32 + (r >> 2) * 8 + hi * 4 + (r & 3);
                            if (kg > qg) x = NEG_INF;
                        }
                        sacc[kh][r] = x;
                        tmax = fmaxf(tmax, x);
                    }
                }
                tmax = fmaxf(tmax, __shfl_xor(tmax, 32, 64));  // full k-row max

                // defer-max: rescale only when the running max grows past THR
                if (__any(tmax > m + 8.0f)) {
                    float mnew = fmaxf(m, tmax);
                    float al = EXP2F(m - mnew);
                    m = mnew; l *= al;
                    #pragma unroll
                    for (int dh = 0; dh < 2; ++dh)
                        #pragma unroll
                        for (int r = 0; r < 16; ++r) oacc[dh][r] *= al;
                }

                float ps = 0.f;
                #pragma unroll
                for (int kh = 0; kh < 2; ++kh)
                    #pragma unroll
                    for (int r = 0; r < 16; ++r) {
                        float p = EXP2F(sacc[kh][r] - m);
                        sacc[kh][r] = p;                        // reuse as P storage
                        ps += p;
                    }
                ps += __shfl_xor(ps, 32, 64);
                l += ps;

                // P^T B-fragments in-register: cvt_pk pairs + permlane32_swap.
                bf16x8 pb[4];
                #pragma unroll
                for (int i = 0; i < 4; ++i) {
                    const int kh = i >> 1, ro = (i & 1) * 8;
                    unsigned pa = pack_bf2(sacc[kh][ro + 0], sacc[kh][ro + 1]);
                    unsigned pe = pack_bf2(sacc[kh][ro + 4], sacc[kh][ro + 5]);
                    unsigned pc = pack_bf2(sacc[kh][ro + 2], sacc[kh][ro + 3]);
                    unsigned pd = pack_bf2(sacc[kh][ro + 6], sacc[kh][ro + 7]);
                    asm("v_permlane32_swap_b32 %0, %1" : "+v"(pa), "+v"(pe));  // pa=w0, pe=w2
                    asm("v_permlane32_swap_b32 %0, %1" : "+v"(pc), "+v"(pd));  // pc=w1, pd=w3
                    union { unsigned u[4]; bf16x8 v; } uu;
                    uu.u[0] = pa; uu.u[1] = pc; uu.u[2] = pe; uu.u[3] = pd;
                    pb[i] = uu.v;
                }

                // O^T += V^T . P^T : two 32-row d-halves, contraction k=64 (4 x K=16)
                __builtin_amdgcn_s_setprio(1);
                #pragma unroll
                for (int dh = 0; dh < 2; ++dh)
                    #pragma unroll
                    for (int i = 0; i < 4; ++i) {
                        bf16x8 vf = *(const bf16x8*)&Vl[slot][cc][dh * 32 + lq][(((i << 1) | hi) ^ rdsw) * 8];
                        oacc[dh] = __builtin_amdgcn_mfma_f32_32x32x16_bf16(vf, pb[i], oacc[dh], 0, 0, 0);
                    }
                __builtin_amdgcn_s_setprio(0);
            }
        }

        // epilogue: lane owns q = Q0+lq; d = dh*32 + g*8 + hi*4 + 0..3 (8B stores)
        float inv = 1.0f / l;
        size_t orow = (size_t)(b * T + Q0 + lq) * C + h * 64;
        #pragma unroll
        for (int dh = 0; dh < 2; ++dh)
            #pragma unroll
            for (int g = 0; g < 4; ++g) {
                ushort4 o4;
                o4.x = f2bf(oacc[dh][g * 4 + 0] * inv);
                o4.y = f2bf(oacc[dh][g * 4 + 1] * inv);
                o4.z = f2bf(oacc[dh][g * 4 + 2] * inv);
                o4.w = f2bf(oacc[dh][g * 4 + 3] * inv);
                *(ushort4*)(O + orow + dh * 32 + g * 8 + hi * 4) = o4;
            }
    }
}

extern "C" void kernel_launch(void* const* d_in, const int* in_sizes, int n_in,
                              void* d_out, int out_size, void* d_ws, size_t ws_size,
                              hipStream_t stream) {
    const float* x  = (const float*)d_in[0];
    const int* tm   = (const int*)d_in[1];
    const float* wq = (const float*)d_in[2]; const float* bq = (const float*)d_in[3];
    const float* wk = (const float*)d_in[4]; const float* bk = (const float*)d_in[5];
    const float* wv = (const float*)d_in[6]; const float* bv = (const float*)d_in[7];
    const float* wp = (const float*)d_in[8]; const float* bp = (const float*)d_in[9];
    float* out = (float*)d_out;

    const int Bv = 4, Tv = 2048, Cv = 1024;
    const size_t MT = (size_t)Bv * Tv;           // 8192 rows
    const size_t XN = MT * Cv;
    const size_t WN = (size_t)Cv * Cv;

    // layout (bf16): xb | wq wk wv (fused 3072x1024) | wp | Q | K | Vt
    unsigned short* xb  = (unsigned short*)d_ws;
    unsigned short* wqb = xb  + XN;
    unsigned short* wkb = wqb + WN;
    unsigned short* wvb = wkb + WN;
    unsigned short* wpb = wvb + WN;
    unsigned short* Qb  = wpb + WN;
    unsigned short* Kb  = Qb + XN;
    unsigned short* Vtb = Kb + XN;               // transposed V [bh][d][t]
    unsigned short* Ab  = xb;                    // attn output reuses xb
    // maskadd scratch lives at the start of d_out (overwritten by the final
    // projection only after attn completes; stream-ordered => safe)
    float* maskadd = (float*)d_out;

    // fused prep: x->bf16 (8192 blocks) | weights->bf16 (4096) | mask (32)
    prep_all<<<12320, 256, 0, stream>>>(x, wq, wk, wv, wp, tm,
                                        xb, wqb, wkb, wvb, wpb, maskadd);

    // fused QKV: logical N = 3072; V portion stored transposed into Vtb
    gemm_bt<<<dim3(24, 64), 256, 0, stream>>>(xb, wqb, bq, bk, bv, nullptr, Qb, Vtb, (int)MT, 3072, Cv);

    attn_kernel<<<dim3(8, Bv * 16), 256, 0, stream>>>(Qb, Kb, Vtb, maskadd, Ab);

    gemm_bt<<<dim3(8, 64), 256, 0, stream>>>(Ab, wpb, bp, bp, bp, out, nullptr, nullptr, (int)MT, 1024, Cv);
}